// Round 15
// baseline (180.416 us; speedup 1.0000x reference)
//
#include <hip/hip_runtime.h>
#include <hip/hip_bf16.h>
#include <hip/hip_fp16.h>
#include <math.h>

#ifndef M_PI
#define M_PI 3.14159265358979323846
#endif

// Problem constants
#define NN 10000      // nodes
#define NE 160000     // edges
#define NC 16         // channels
#define NQ 5          // 2*order+1
#define NFR 10        // N_FREQ * N_RINGS
#define CQ 80         // NC*NQ
#define OP 80         // outputs per node

// Fixed-bucket edge store: node n owns slots [n*MAXDEG, n*MAXDEG+deg).
#define MAXDEG 64

// Extended GEMM: k in [0,800) edge part (k = cq*10 + fr); k in [800,880)
// self part (k = 800 + cq); k in [880,896) zero pad (A and B both zero).
#define KTOT2 896
#define KS 28         // 896 / 32 MFMA k-steps
#define WTN 71680     // KTOT2 * 80 weight elements per layer
#define APAD 936      // LDS row stride fp16 (20 mod 32 banks, v12-proven)
#define NPB 8         // nodes per block (8 waves, 512 threads)

typedef __attribute__((ext_vector_type(8))) _Float16 f16x8;
typedef __attribute__((ext_vector_type(4))) float f32x4;

static __device__ __forceinline__ unsigned short f2h_u(float f) {
    return __builtin_bit_cast(unsigned short, (_Float16)f);
}
static __device__ __forceinline__ unsigned pack2h(float lo, float hi) {
    return (unsigned)f2h_u(lo) | ((unsigned)f2h_u(hi) << 16);
}
#define RFL(x) __builtin_amdgcn_readfirstlane(x)

// ---------------------------------------------------------------------------
// prep_all: ONE dispatch does everything the layers need (unchanged, verified).
// ---------------------------------------------------------------------------
__global__ void prep_all(const int* __restrict__ ei, const float* __restrict__ phi,
                         const float* __restrict__ pre,
                         const float* __restrict__ W1, const float* __restrict__ Ws1,
                         const float* __restrict__ W2, const float* __restrict__ Ws2,
                         int* __restrict__ cnt, int* __restrict__ srcs,
                         float4* __restrict__ recs,
                         unsigned short* __restrict__ Wt1, unsigned short* __restrict__ Wt2) {
    int i = blockIdx.x * blockDim.x + threadIdx.x;
    if (i < NE) {
        const int dst  = ei[2 * i + 1];
        const int srcn = ei[2 * i];
        const int rank = atomicAdd(&cnt[dst], 1);
        if (rank < MAXDEG) {
            float s1, c1;
            sincosf(phi[i], &s1, &c1);
            const float* tp = pre + (size_t)i * NFR;
            const int slot = dst * MAXDEG + rank;
            float4* rp = recs + (size_t)slot * 3;
            rp[0] = make_float4(tp[0], tp[1], tp[2], tp[3]);
            rp[1] = make_float4(tp[4], tp[5], tp[6], tp[7]);
            rp[2] = make_float4(tp[8], tp[9], c1, s1);
            srcs[slot] = srcn;
        }
    }
    if (i < WTN) {
        int j    = i & 7;
        int lane = (i >> 3) & 63;
        int grp  = i >> 9;            // 0..139 = ks*5 + nt
        int ks   = grp / 5;
        int nt   = grp % 5;
        int quad = lane >> 4;
        int lrow = lane & 15;
        int n    = 16 * nt + lrow;    // output index op
        int k    = 32 * ks + 8 * quad + j;
        int o = n / 5, p = n % 5;
        float v1, v2;
        if (k < 800) {                // edge part: k = cq*10 + fr
            int cq = k / 10, fr = k % 10;
            int c = cq / 5, q = cq % 5;
            int f = fr >> 1, r = fr & 1;
            int src = ((((o * NC + c) * NQ + p) * NQ + q) * 5 + f) * 2 + r;
            v1 = W1[src]; v2 = W2[src];
        } else if (k < 880) {         // self part: k = 800 + cq
            int cq = k - 800;
            int c = cq / 5, q = cq % 5;
            int src = ((o * NC + c) * NQ + p) * NQ + q;
            v1 = Ws1[src]; v2 = Ws2[src];
        } else {                      // pad
            v1 = 0.0f; v2 = 0.0f;
        }
        Wt1[i] = f2h_u(v1); Wt2[i] = f2h_u(v2);
    }
}

// ---------------------------------------------------------------------------
// layer_fused v25 = v22 (best: 8 nodes / 512 thr, 1 wave/node, depth-2
// record pipeline) with the record stream moved SCALAR -> VECTOR pipe.
//
// Mechanism (R14 diagnosis): v22's wave-uniform srcs/recs loads compile to
// s_load (SGPR state: VGPR=32/SGPR~100). SMEM returns out-of-order, so the
// compiler must drain lgkmcnt(0) before each use — killing every software
// prefetch (including the ones just issued) and serializing the loop on
// scalar-memory latency. The low-concurrency scalar pipe shared by 32
// waves/CU is the ~40 us/layer wall; this is why depth-2/3 pipelining and
// the 2-wave split were all null-to-negative.
//
// Fix: asm("" : "+v"(slot)) blocks uniformity analysis -> srcs/recs loads
// become VECTOR loads (all lanes same address = one broadcast L2 request),
// tracked by vmcnt: in-order, fine-grained s_waitcnt vmcnt(N) -> the depth-2
// pipeline finally keeps loads in flight. Values/order bit-identical to v22.
// ---------------------------------------------------------------------------
__global__ __launch_bounds__(512)
void layer_fused(const float* __restrict__ xin, const int* __restrict__ srcs,
                 const float4* __restrict__ recs, const int* __restrict__ cnt,
                 const unsigned short* __restrict__ Wt, const float* __restrict__ b,
                 const float* __restrict__ res,   // residual (x) or nullptr
                 float* __restrict__ outp) {
    __shared__ __align__(16) unsigned short A_s[NPB * APAD];  // 14,976 B
    __shared__ float y_s[NPB * OP];                           //  2,560 B

    const int tid = threadIdx.x;
    const int n0 = blockIdx.x * NPB;             // NN = 1250*8 exactly
    const int wid = RFL(tid >> 6);               // wave id = local node (SGPR)
    const int lane = tid & 63;
    const int n = n0 + wid;

    // ---- lane roles (lanes 48..63 clamped to in-bounds dummy work) ----
    const int l48 = (lane < 48) ? lane : 0;
    const int c   = l48 / 3;
    const int g   = l48 - 3 * c;                 // 0,1,2
    const int cqA = 5 * c + ((g == 0) ? 0 : (g == 1) ? 1 : 3);
    const int cqB = cqA + 1;                     // partner (ignored for g==0)
    const bool hi = (g == 2);

    const int base = n * MAXDEG;
    int deg = RFL(cnt[n]);
    if (deg > MAXDEG) deg = MAXDEG;

    float accA[10], accB[10];
    #pragma unroll
    for (int f = 0; f < 10; ++f) { accA[f] = 0.f; accB[f] = 0.f; }

#define EDGE_FMA(r0, r1, r2, xa, xb)                                          \
    do {                                                                      \
        const float c1 = (r2).z, s1 = (r2).w;                                 \
        const float c2 = c1 * c1 - s1 * s1;                                   \
        const float s2 = 2.0f * c1 * s1;                                      \
        const float cs = hi ? c2 : c1;                                        \
        const float sn = hi ? s2 : s1;                                        \
        const float xtA = (g == 0) ? (xa) : (cs * (xa) - sn * (xb));          \
        const float xtB = sn * (xa) + cs * (xb);                              \
        accA[0] += xtA * (r0).x;  accB[0] += xtB * (r0).x;                    \
        accA[1] += xtA * (r0).y;  accB[1] += xtB * (r0).y;                    \
        accA[2] += xtA * (r0).z;  accB[2] += xtB * (r0).z;                    \
        accA[3] += xtA * (r0).w;  accB[3] += xtB * (r0).w;                    \
        accA[4] += xtA * (r1).x;  accB[4] += xtB * (r1).x;                    \
        accA[5] += xtA * (r1).y;  accB[5] += xtB * (r1).y;                    \
        accA[6] += xtA * (r1).z;  accB[6] += xtB * (r1).z;                    \
        accA[7] += xtA * (r1).w;  accB[7] += xtB * (r1).w;                    \
        accA[8] += xtA * (r2).x;  accB[8] += xtB * (r2).x;                    \
        accA[9] += xtA * (r2).y;  accB[9] += xtB * (r2).y;                    \
    } while (0)

    // VSLOT: clamped bucket index FORCED into a VGPR (blocks the compiler's
    // uniformity analysis -> vector loads on the vmcnt-tracked pipe).
#define VSLOT(v, i)                                                           \
    int v = base + (((i) < deg) ? (i) : (deg - 1));                           \
    asm("" : "+v"(v));

    if (deg > 0) {
        // ---- depth-2 prologue: windows 0 (slots 0,1) and 1 (slots 2,3) ----
        VSLOT(i0, 0) VSLOT(i1, 1) VSLOT(i2, 2) VSLOT(i3, 3)
        int sA0 = srcs[i0];
        int sB0 = srcs[i1];
        int sA1 = srcs[i2];
        int sB1 = srcs[i3];
        const float4* p;
        p = recs + (size_t)i0 * 3; float4 rA0a = p[0], rA0b = p[1], rA0c = p[2];
        p = recs + (size_t)i1 * 3; float4 rB0a = p[0], rB0b = p[1], rB0c = p[2];
        p = recs + (size_t)i2 * 3; float4 rA1a = p[0], rA1b = p[1], rA1c = p[2];
        p = recs + (size_t)i3 * 3; float4 rB1a = p[0], rB1b = p[1], rB1c = p[2];
        const float* xr;
        xr = xin + (size_t)sA0 * CQ; float xaA = xr[cqA], xbA = xr[cqB];
        xr = xin + (size_t)sB0 * CQ; float xaB = xr[cqA], xbB = xr[cqB];

        int i = 0;
        for (; i + 2 <= deg; i += 2) {
            // prefetch srcs + recs for window w+2 (vector, broadcast)
            VSLOT(j0, i + 4) VSLOT(j1, i + 5)
            const int nsA = srcs[j0];
            const int nsB = srcs[j1];
            // prefetch x for window w+1 (addresses ready: sA1/sB1)
            const float* x1 = xin + (size_t)sA1 * CQ;
            const float* x2 = xin + (size_t)sB1 * CQ;
            const float nxaA = x1[cqA], nxbA = x1[cqB];
            const float nxaB = x2[cqA], nxbB = x2[cqB];
            const float4* q1 = recs + (size_t)j0 * 3;
            const float4* q2 = recs + (size_t)j1 * 3;
            const float4 nrAa = q1[0], nrAb = q1[1], nrAc = q1[2];
            const float4 nrBa = q2[0], nrBb = q2[1], nrBc = q2[2];
            // compute window w (slot order preserved -> v22-identical values)
            EDGE_FMA(rA0a, rA0b, rA0c, xaA, xbA);
            EDGE_FMA(rB0a, rB0b, rB0c, xaB, xbB);
            // rotate pipeline state
            sA0 = sA1; sB0 = sB1; sA1 = nsA; sB1 = nsB;
            xaA = nxaA; xbA = nxbA; xaB = nxaB; xbB = nxbB;
            rA0a = rA1a; rA0b = rA1b; rA0c = rA1c;
            rB0a = rB1a; rB0b = rB1b; rB0c = rB1c;
            rA1a = nrAa; rA1b = nrAb; rA1c = nrAc;
            rB1a = nrBa; rB1b = nrBb; rB1c = nrBc;
        }
        if (deg & 1) {   // tail edge deg-1: window-0 state holds slot(deg-1)
            EDGE_FMA(rA0a, rA0b, rA0c, xaA, xbA);
        }
    }
#undef VSLOT
#undef EDGE_FMA

    // ---- A-row write (k = cq*10 + fr), self column, zero pad ----
    if (lane < 48) {
        unsigned* awA = (unsigned*)&A_s[wid * APAD + cqA * 10];
        awA[0] = pack2h(accA[0], accA[1]);
        awA[1] = pack2h(accA[2], accA[3]);
        awA[2] = pack2h(accA[4], accA[5]);
        awA[3] = pack2h(accA[6], accA[7]);
        awA[4] = pack2h(accA[8], accA[9]);
        A_s[wid * APAD + 800 + cqA] = f2h_u(xin[(size_t)n * CQ + cqA]);
        if (g != 0) {
            unsigned* awB = (unsigned*)&A_s[wid * APAD + cqB * 10];
            awB[0] = pack2h(accB[0], accB[1]);
            awB[1] = pack2h(accB[2], accB[3]);
            awB[2] = pack2h(accB[4], accB[5]);
            awB[3] = pack2h(accB[6], accB[7]);
            awB[4] = pack2h(accB[8], accB[9]);
            A_s[wid * APAD + 800 + cqB] = f2h_u(xin[(size_t)n * CQ + cqB]);
        }
    }
    if (lane < 16) A_s[wid * APAD + 880 + lane] = 0;

    __syncthreads();

    // ---- GEMM: y[8 x 80] = A_s[8 x 896] @ B'[896 x 80] (waves 0-4) ----
    // A row = lrow&7 (rows 8-15 duplicate rows 0-7; D rows 8-15 discarded).
    if (tid < 320) {
        const int nt = tid >> 6, lq = tid & 63;
        const int lrow = lq & 15, quad = lq >> 4;
        const int arow = lrow & 7;
        const f16x8* __restrict__ wf = (const f16x8*)Wt;
        f32x4 acc = (f32x4){0.f, 0.f, 0.f, 0.f};
        #pragma unroll 4
        for (int ks = 0; ks < KS; ++ks) {
            f16x8 bfrag = wf[(ks * 5 + nt) * 64 + lq];
            f16x8 a = *(const f16x8*)(&A_s[arow * APAD + 32 * ks + 8 * quad]);
            acc = __builtin_amdgcn_mfma_f32_16x16x32_f16(a, bfrag, acc, 0, 0, 0);
        }
        const int op = 16 * nt + lrow;
        const float bias = (op % 5 == 0) ? b[op / 5] : 0.0f;
        if (quad < 2) {                          // D rows 0..7 only
            #pragma unroll
            for (int r = 0; r < 4; ++r)
                y_s[(quad * 4 + r) * OP + op] = acc[r] + bias;
        }
    }
    __syncthreads();

    // ---- epilogue: 128 threads, one (node, channel) each ----
    if (tid < 128) {
        const int nl = tid >> 4;                 // node 0..7
        const int ch = tid & 15;                 // channel
        const float* vp = &y_s[nl * OP + ch * 5];
        float a0 = vp[0], a1 = vp[1], a2 = vp[2], a3 = vp[3], a4 = vp[4];
        if (res != nullptr) {
            const float* rp = res + (size_t)(n0 + nl) * CQ + ch * 5;
            a0 += rp[0]; a1 += rp[1]; a2 += rp[2]; a3 += rp[3]; a4 += rp[4];
        }
        float o0 = 0.f, o1 = 0.f, o2 = 0.f, o3 = 0.f, o4 = 0.f;
        #pragma unroll
        for (int k = 0; k < 7; ++k) {
            float th = (float)(2.0 * M_PI / 7.0) * (float)k;
            float c1k = cosf(th), s1k = sinf(th);
            float c2k = cosf(2.0f * th), s2k = sinf(2.0f * th);
            float s = a0 + a1 * c1k + a2 * s1k + a3 * c2k + a4 * s2k;
            s = fmaxf(s, 0.0f);
            o0 += s;
            o1 += s * c1k; o2 += s * s1k;
            o3 += s * c2k; o4 += s * s2k;
        }
        const float i7 = 1.0f / 7.0f, t7 = 2.0f / 7.0f;
        float* po = outp + (size_t)(n0 + nl) * OP + ch * 5;
        po[0] = o0 * i7;
        po[1] = o1 * t7; po[2] = o2 * t7;
        po[3] = o3 * t7; po[4] = o4 * t7;
    }
}

// ---------------------------------------------------------------------------
extern "C" void kernel_launch(void* const* d_in, const int* in_sizes, int n_in,
                              void* d_out, int out_size, void* d_ws, size_t ws_size,
                              hipStream_t stream) {
    const float* x    = (const float*)d_in[0];
    const int*   ei   = (const int*)d_in[1];      // int inputs arrive as int32
    const float* pre  = (const float*)d_in[2];
    const float* phi  = (const float*)d_in[3];
    const float* W1   = (const float*)d_in[4];
    const float* b1   = (const float*)d_in[5];
    const float* Ws1  = (const float*)d_in[6];
    const float* W2   = (const float*)d_in[7];
    const float* b2   = (const float*)d_in[8];
    const float* Ws2  = (const float*)d_in[9];
    float* out = (float*)d_out;

    // Workspace layout (~37 MB of the 256 MB ws)
    unsigned short* Wt1 = (unsigned short*)d_ws;            // 143.4 KB
    unsigned short* Wt2 = Wt1 + WTN;                        // 143.4 KB
    float* h  = (float*)(Wt2 + WTN);                        // 3.2 MB
    float4* recs = (float4*)(h + (size_t)NN * OP);          // 30.72 MB (16B aligned)
    int* srcs   = (int*)(recs + (size_t)NN * MAXDEG * 3);   // 2.56 MB
    int* cnt    = srcs + (size_t)NN * MAXDEG;               // 40 KB

    // 4-dispatch chain: memset -> prep_all -> layer1 -> layer2
    hipMemsetAsync(cnt, 0, NN * sizeof(int), stream);
    prep_all<<<(NE + 255) / 256, 256, 0, stream>>>(ei, phi, pre, W1, Ws1, W2, Ws2,
                                                   cnt, srcs, recs, Wt1, Wt2);
    layer_fused<<<NN / NPB, 512, 0, stream>>>(x, srcs, recs, cnt, Wt1, b1, nullptr, h);
    layer_fused<<<NN / NPB, 512, 0, stream>>>(h, srcs, recs, cnt, Wt2, b2, x, out);
}

// Round 16
// 156.072 us; speedup vs baseline: 1.1560x; 1.1560x over previous
//
#include <hip/hip_runtime.h>
#include <hip/hip_bf16.h>
#include <hip/hip_fp16.h>
#include <math.h>

#ifndef M_PI
#define M_PI 3.14159265358979323846
#endif

// Problem constants
#define NN 10000      // nodes
#define NE 160000     // edges
#define NC 16         // channels
#define NQ 5          // 2*order+1
#define NFR 10        // N_FREQ * N_RINGS
#define CQ 80         // NC*NQ
#define OP 80         // outputs per node

// Fixed-bucket edge store: node n owns slots [n*MAXDEG, n*MAXDEG+deg).
// Buckets are ZERO-INITIALIZED (pad slots: tv=0 -> contributes exactly 0).
#define MAXDEG 64

// Extended GEMM: k in [0,800) edge part (k = cq*10 + fr); k in [800,880)
// self part (k = 800 + cq); k in [880,896) zero pad (A and B both zero).
#define KTOT2 896
#define KS 28         // 896 / 32 MFMA k-steps
#define WTN 71680     // KTOT2 * 80 weight elements per layer
#define APAD 936      // LDS row stride fp16 (20 mod 32 banks, v12-proven)
#define NPB 8         // nodes per block (8 waves, 512 threads)

typedef __attribute__((ext_vector_type(8))) _Float16 f16x8;
typedef __attribute__((ext_vector_type(4))) float f32x4;

static __device__ __forceinline__ unsigned short f2h_u(float f) {
    return __builtin_bit_cast(unsigned short, (_Float16)f);
}
static __device__ __forceinline__ unsigned pack2h(float lo, float hi) {
    return (unsigned)f2h_u(lo) | ((unsigned)f2h_u(hi) << 16);
}
#define RFL(x) __builtin_amdgcn_readfirstlane(x)
// lane-broadcast of a float held per-lane (v_readlane: EXEC-independent)
static __device__ __forceinline__ float rdl(float v, int l) {
    return __builtin_bit_cast(float, __builtin_amdgcn_readlane(__builtin_bit_cast(int, v), l));
}

// ---------------------------------------------------------------------------
// prep_all: ONE dispatch does everything the layers need (unchanged, verified).
// ---------------------------------------------------------------------------
__global__ void prep_all(const int* __restrict__ ei, const float* __restrict__ phi,
                         const float* __restrict__ pre,
                         const float* __restrict__ W1, const float* __restrict__ Ws1,
                         const float* __restrict__ W2, const float* __restrict__ Ws2,
                         int* __restrict__ cnt, int* __restrict__ srcs,
                         float4* __restrict__ recs,
                         unsigned short* __restrict__ Wt1, unsigned short* __restrict__ Wt2) {
    int i = blockIdx.x * blockDim.x + threadIdx.x;
    if (i < NE) {
        const int dst  = ei[2 * i + 1];
        const int srcn = ei[2 * i];
        const int rank = atomicAdd(&cnt[dst], 1);
        if (rank < MAXDEG) {
            float s1, c1;
            sincosf(phi[i], &s1, &c1);
            const float* tp = pre + (size_t)i * NFR;
            const int slot = dst * MAXDEG + rank;
            float4* rp = recs + (size_t)slot * 3;
            rp[0] = make_float4(tp[0], tp[1], tp[2], tp[3]);
            rp[1] = make_float4(tp[4], tp[5], tp[6], tp[7]);
            rp[2] = make_float4(tp[8], tp[9], c1, s1);
            srcs[slot] = srcn;
        }
    }
    if (i < WTN) {
        int j    = i & 7;
        int lane = (i >> 3) & 63;
        int grp  = i >> 9;            // 0..139 = ks*5 + nt
        int ks   = grp / 5;
        int nt   = grp % 5;
        int quad = lane >> 4;
        int lrow = lane & 15;
        int n    = 16 * nt + lrow;    // output index op
        int k    = 32 * ks + 8 * quad + j;
        int o = n / 5, p = n % 5;
        float v1, v2;
        if (k < 800) {                // edge part: k = cq*10 + fr
            int cq = k / 10, fr = k % 10;
            int c = cq / 5, q = cq % 5;
            int f = fr >> 1, r = fr & 1;
            int src = ((((o * NC + c) * NQ + p) * NQ + q) * 5 + f) * 2 + r;
            v1 = W1[src]; v2 = W2[src];
        } else if (k < 880) {         // self part: k = 800 + cq
            int cq = k - 800;
            int c = cq / 5, q = cq % 5;
            int src = ((o * NC + c) * NQ + p) * NQ + q;
            v1 = Ws1[src]; v2 = Ws2[src];
        } else {                      // pad
            v1 = 0.0f; v2 = 0.0f;
        }
        Wt1[i] = f2h_u(v1); Wt2[i] = f2h_u(v2);
    }
}

// ---------------------------------------------------------------------------
// layer_fused v26: LATENCY-BATCHED aggregation (GEMM/epilogue = verified v22).
//
// R15 counters (layer visible at last): VALUBusy 27.6% / MfmaUtil 2.2% /
// 425 GB/s — pure latency bound, matching the model "8 waves/SIMD x ~60cy
// work per ~460cy period" (8x60/460 = 28%). Every prior variant exposed
// ~400cy of load latency once per 2 edges.
//
// v26 aggregation:
//  1. PER-LANE RECORD OWNERSHIP: lane l loads bucket slot l's record + src
//     (4 coalesced VMEM per node, once). Buckets zero-padded (extended
//     memset): pad tv=0 -> +0.0 exactly, no guards anywhere.
//  2. Compute-time broadcast via v_readlane (VALU, EXEC-independent):
//     12 scalars/edge, ZERO memory ops in the FMA loop.
//  3. x-gathers issued 8-at-a-time (chunk of 4 edges, addresses from
//     readlane'd srcs): one vmcnt drain per 4 edges, no rotation movs.
//  VGPR ~55 (acc 20 + rec 13 + xbuf 8 + misc) -> 8 waves/SIMD preserved.
//  Slot order & FMA order unchanged -> bit-identical values to v22.
// ---------------------------------------------------------------------------
__global__ __launch_bounds__(512)
void layer_fused(const float* __restrict__ xin, const int* __restrict__ srcs,
                 const float4* __restrict__ recs, const int* __restrict__ cnt,
                 const unsigned short* __restrict__ Wt, const float* __restrict__ b,
                 const float* __restrict__ res,   // residual (x) or nullptr
                 float* __restrict__ outp) {
    __shared__ __align__(16) unsigned short A_s[NPB * APAD];  // 14,976 B
    __shared__ float y_s[NPB * OP];                           //  2,560 B

    const int tid = threadIdx.x;
    const int n0 = blockIdx.x * NPB;             // NN = 1250*8 exactly
    const int wid = RFL(tid >> 6);               // wave id = local node (SGPR)
    const int lane = tid & 63;
    const int n = n0 + wid;

    // ---- lane roles (lanes 48..63 clamped to in-bounds dummy work) ----
    const int l48 = (lane < 48) ? lane : 0;
    const int c   = l48 / 3;
    const int g   = l48 - 3 * c;                 // 0,1,2
    const int cqA = 5 * c + ((g == 0) ? 0 : (g == 1) ? 1 : 3);
    const int cqB = cqA + 1;                     // partner (ignored for g==0)
    const bool hi = (g == 2);

    const int base = n * MAXDEG;
    int deg = RFL(cnt[n]);
    if (deg > MAXDEG) deg = MAXDEG;

    // ---- per-lane record ownership: lane l <-> bucket slot l (zero pads) ----
    const int lslot = base + lane;               // always in-bounds (lane<64)
    const int my_src = srcs[lslot];              // 0 for pad slots
    const float4* lrp = recs + (size_t)lslot * 3;
    const float4 my_r0 = lrp[0];
    const float4 my_r1 = lrp[1];
    const float4 my_r2 = lrp[2];

    float accA[10], accB[10];
    #pragma unroll
    for (int f = 0; f < 10; ++f) { accA[f] = 0.f; accB[f] = 0.f; }

    // EDGE_RL: broadcast edge le's record from its owning lane (readlane ->
    // SGPR), then accumulate. t* are scalar (SGPR) -> 1-SGPR-per-VALU ok.
#define EDGE_RL(le, xa, xb)                                                   \
    do {                                                                      \
        const float t0 = rdl(my_r0.x, le), t1 = rdl(my_r0.y, le);             \
        const float t2 = rdl(my_r0.z, le), t3 = rdl(my_r0.w, le);             \
        const float t4 = rdl(my_r1.x, le), t5 = rdl(my_r1.y, le);             \
        const float t6 = rdl(my_r1.z, le), t7 = rdl(my_r1.w, le);             \
        const float t8 = rdl(my_r2.x, le), t9 = rdl(my_r2.y, le);             \
        const float c1 = rdl(my_r2.z, le), s1 = rdl(my_r2.w, le);             \
        const float c2 = c1 * c1 - s1 * s1;                                   \
        const float s2 = 2.0f * c1 * s1;                                      \
        const float cs = hi ? c2 : c1;                                        \
        const float sn = hi ? s2 : s1;                                        \
        const float xtA = (g == 0) ? (xa) : (cs * (xa) - sn * (xb));          \
        const float xtB = sn * (xa) + cs * (xb);                              \
        accA[0] += xtA * t0;  accB[0] += xtB * t0;                            \
        accA[1] += xtA * t1;  accB[1] += xtB * t1;                            \
        accA[2] += xtA * t2;  accB[2] += xtB * t2;                            \
        accA[3] += xtA * t3;  accB[3] += xtB * t3;                            \
        accA[4] += xtA * t4;  accB[4] += xtB * t4;                            \
        accA[5] += xtA * t5;  accB[5] += xtB * t5;                            \
        accA[6] += xtA * t6;  accB[6] += xtB * t6;                            \
        accA[7] += xtA * t7;  accB[7] += xtB * t7;                            \
        accA[8] += xtA * t8;  accB[8] += xtB * t8;                            \
        accA[9] += xtA * t9;  accB[9] += xtB * t9;                            \
    } while (0)

    // ---- chunked edge loop: 4 edges/chunk, pads contribute exactly 0 ----
    const int nch = (deg + 3) >> 2;              // uniform
    for (int ch = 0; ch < nch; ++ch) {
        const int e0 = ch << 2;
        // srcs -> SGPR via readlane; issue 8 INDEPENDENT x-gathers
        const int s0 = __builtin_amdgcn_readlane(my_src, e0 + 0);
        const int s1 = __builtin_amdgcn_readlane(my_src, e0 + 1);
        const int s2 = __builtin_amdgcn_readlane(my_src, e0 + 2);
        const int s3 = __builtin_amdgcn_readlane(my_src, e0 + 3);
        const float* p0 = xin + (size_t)s0 * CQ;
        const float* p1 = xin + (size_t)s1 * CQ;
        const float* p2 = xin + (size_t)s2 * CQ;
        const float* p3 = xin + (size_t)s3 * CQ;
        const float xa0 = p0[cqA], xb0 = p0[cqB];
        const float xa1 = p1[cqA], xb1 = p1[cqB];
        const float xa2 = p2[cqA], xb2 = p2[cqB];
        const float xa3 = p3[cqA], xb3 = p3[cqB];
        // accumulate in slot order (bit-identical to v22)
        EDGE_RL(e0 + 0, xa0, xb0);
        EDGE_RL(e0 + 1, xa1, xb1);
        EDGE_RL(e0 + 2, xa2, xb2);
        EDGE_RL(e0 + 3, xa3, xb3);
    }
#undef EDGE_RL

    // ---- A-row write (k = cq*10 + fr), self column, zero pad ----
    if (lane < 48) {
        unsigned* awA = (unsigned*)&A_s[wid * APAD + cqA * 10];
        awA[0] = pack2h(accA[0], accA[1]);
        awA[1] = pack2h(accA[2], accA[3]);
        awA[2] = pack2h(accA[4], accA[5]);
        awA[3] = pack2h(accA[6], accA[7]);
        awA[4] = pack2h(accA[8], accA[9]);
        A_s[wid * APAD + 800 + cqA] = f2h_u(xin[(size_t)n * CQ + cqA]);
        if (g != 0) {
            unsigned* awB = (unsigned*)&A_s[wid * APAD + cqB * 10];
            awB[0] = pack2h(accB[0], accB[1]);
            awB[1] = pack2h(accB[2], accB[3]);
            awB[2] = pack2h(accB[4], accB[5]);
            awB[3] = pack2h(accB[6], accB[7]);
            awB[4] = pack2h(accB[8], accB[9]);
            A_s[wid * APAD + 800 + cqB] = f2h_u(xin[(size_t)n * CQ + cqB]);
        }
    }
    if (lane < 16) A_s[wid * APAD + 880 + lane] = 0;

    __syncthreads();

    // ---- GEMM: y[8 x 80] = A_s[8 x 896] @ B'[896 x 80] (waves 0-4) ----
    // A row = lrow&7 (rows 8-15 duplicate rows 0-7; D rows 8-15 discarded).
    if (tid < 320) {
        const int nt = tid >> 6, lq = tid & 63;
        const int lrow = lq & 15, quad = lq >> 4;
        const int arow = lrow & 7;
        const f16x8* __restrict__ wf = (const f16x8*)Wt;
        f32x4 acc = (f32x4){0.f, 0.f, 0.f, 0.f};
        #pragma unroll 4
        for (int ks = 0; ks < KS; ++ks) {
            f16x8 bfrag = wf[(ks * 5 + nt) * 64 + lq];
            f16x8 a = *(const f16x8*)(&A_s[arow * APAD + 32 * ks + 8 * quad]);
            acc = __builtin_amdgcn_mfma_f32_16x16x32_f16(a, bfrag, acc, 0, 0, 0);
        }
        const int op = 16 * nt + lrow;
        const float bias = (op % 5 == 0) ? b[op / 5] : 0.0f;
        if (quad < 2) {                          // D rows 0..7 only
            #pragma unroll
            for (int r = 0; r < 4; ++r)
                y_s[(quad * 4 + r) * OP + op] = acc[r] + bias;
        }
    }
    __syncthreads();

    // ---- epilogue: 128 threads, one (node, channel) each ----
    if (tid < 128) {
        const int nl = tid >> 4;                 // node 0..7
        const int ch = tid & 15;                 // channel
        const float* vp = &y_s[nl * OP + ch * 5];
        float a0 = vp[0], a1 = vp[1], a2 = vp[2], a3 = vp[3], a4 = vp[4];
        if (res != nullptr) {
            const float* rp = res + (size_t)(n0 + nl) * CQ + ch * 5;
            a0 += rp[0]; a1 += rp[1]; a2 += rp[2]; a3 += rp[3]; a4 += rp[4];
        }
        float o0 = 0.f, o1 = 0.f, o2 = 0.f, o3 = 0.f, o4 = 0.f;
        #pragma unroll
        for (int k = 0; k < 7; ++k) {
            float th = (float)(2.0 * M_PI / 7.0) * (float)k;
            float c1k = cosf(th), s1k = sinf(th);
            float c2k = cosf(2.0f * th), s2k = sinf(2.0f * th);
            float s = a0 + a1 * c1k + a2 * s1k + a3 * c2k + a4 * s2k;
            s = fmaxf(s, 0.0f);
            o0 += s;
            o1 += s * c1k; o2 += s * s1k;
            o3 += s * c2k; o4 += s * s2k;
        }
        const float i7 = 1.0f / 7.0f, t7 = 2.0f / 7.0f;
        float* po = outp + (size_t)(n0 + nl) * OP + ch * 5;
        po[0] = o0 * i7;
        po[1] = o1 * t7; po[2] = o2 * t7;
        po[3] = o3 * t7; po[4] = o4 * t7;
    }
}

// ---------------------------------------------------------------------------
extern "C" void kernel_launch(void* const* d_in, const int* in_sizes, int n_in,
                              void* d_out, int out_size, void* d_ws, size_t ws_size,
                              hipStream_t stream) {
    const float* x    = (const float*)d_in[0];
    const int*   ei   = (const int*)d_in[1];      // int inputs arrive as int32
    const float* pre  = (const float*)d_in[2];
    const float* phi  = (const float*)d_in[3];
    const float* W1   = (const float*)d_in[4];
    const float* b1   = (const float*)d_in[5];
    const float* Ws1  = (const float*)d_in[6];
    const float* W2   = (const float*)d_in[7];
    const float* b2   = (const float*)d_in[8];
    const float* Ws2  = (const float*)d_in[9];
    float* out = (float*)d_out;

    // Workspace layout (~37 MB of the 256 MB ws).
    // recs | srcs | cnt are CONTIGUOUS -> one zeroing memset covers all
    // (zero pads make the chunked edge loop guard-free).
    unsigned short* Wt1 = (unsigned short*)d_ws;            // 143.4 KB
    unsigned short* Wt2 = Wt1 + WTN;                        // 143.4 KB
    float* h  = (float*)(Wt2 + WTN);                        // 3.2 MB
    float4* recs = (float4*)(h + (size_t)NN * OP);          // 30.72 MB (16B aligned)
    int* srcs   = (int*)(recs + (size_t)NN * MAXDEG * 3);   // 2.56 MB
    int* cnt    = srcs + (size_t)NN * MAXDEG;               // 40 KB
    const size_t zbytes = (size_t)NN * MAXDEG * 3 * sizeof(float4)
                        + (size_t)NN * MAXDEG * sizeof(int)
                        + (size_t)NN * sizeof(int);         // 33.32 MB

    // 4-dispatch chain: memset(recs+srcs+cnt) -> prep_all -> layer1 -> layer2
    hipMemsetAsync(recs, 0, zbytes, stream);
    prep_all<<<(NE + 255) / 256, 256, 0, stream>>>(ei, phi, pre, W1, Ws1, W2, Ws2,
                                                   cnt, srcs, recs, Wt1, Wt2);
    layer_fused<<<NN / NPB, 512, 0, stream>>>(x, srcs, recs, cnt, Wt1, b1, nullptr, h);
    layer_fused<<<NN / NPB, 512, 0, stream>>>(h, srcs, recs, cnt, Wt2, b2, x, out);
}

// Round 17
// 145.742 us; speedup vs baseline: 1.2379x; 1.0709x over previous
//
#include <hip/hip_runtime.h>
#include <hip/hip_bf16.h>
#include <hip/hip_fp16.h>
#include <math.h>

#ifndef M_PI
#define M_PI 3.14159265358979323846
#endif

// Problem constants
#define NN 10000      // nodes
#define NE 160000     // edges
#define NC 16         // channels
#define NQ 5          // 2*order+1
#define NFR 10        // N_FREQ * N_RINGS
#define CQ 80         // NC*NQ
#define OP 80         // outputs per node

// Fixed-bucket edge store: node n owns slots [n*MAXDEG, n*MAXDEG+deg).
// deg ~ Binomial(160000,1e-4): mean 16, sd 4; 64 = 12 sd -> safe for any seed.
#define MAXDEG 64

// Extended GEMM: k in [0,800) edge part (k = cq*10 + fr); k in [800,880)
// self part (k = 800 + cq); k in [880,896) zero pad (A and B both zero).
#define KTOT2 896
#define KS 28         // 896 / 32 MFMA k-steps
#define WTN 71680     // KTOT2 * 80 weight elements per layer
#define APAD 936      // LDS row stride fp16 (20 mod 32 banks, v12-proven)
#define NPB 8         // nodes per block (8 waves, 512 threads)

typedef __attribute__((ext_vector_type(8))) _Float16 f16x8;
typedef __attribute__((ext_vector_type(4))) float f32x4;

static __device__ __forceinline__ unsigned short f2h_u(float f) {
    return __builtin_bit_cast(unsigned short, (_Float16)f);
}
static __device__ __forceinline__ unsigned pack2h(float lo, float hi) {
    return (unsigned)f2h_u(lo) | ((unsigned)f2h_u(hi) << 16);
}
#define RFL(x) __builtin_amdgcn_readfirstlane(x)

// ---------------------------------------------------------------------------
// prep_all: ONE dispatch does everything the layers need.
//  i < NE:  edge i claims rank = atomicAdd(cnt[dst]) and writes its record
//           {tv[0..9], c1, s1} (48 B) + src id into node dst's fixed bucket.
//  i < WTN: reorder W+Ws into MFMA-B fragment order (k-map above, R10-proven).
// ---------------------------------------------------------------------------
__global__ void prep_all(const int* __restrict__ ei, const float* __restrict__ phi,
                         const float* __restrict__ pre,
                         const float* __restrict__ W1, const float* __restrict__ Ws1,
                         const float* __restrict__ W2, const float* __restrict__ Ws2,
                         int* __restrict__ cnt, int* __restrict__ srcs,
                         float4* __restrict__ recs,
                         unsigned short* __restrict__ Wt1, unsigned short* __restrict__ Wt2) {
    int i = blockIdx.x * blockDim.x + threadIdx.x;
    if (i < NE) {
        const int dst  = ei[2 * i + 1];
        const int srcn = ei[2 * i];
        const int rank = atomicAdd(&cnt[dst], 1);
        if (rank < MAXDEG) {               // can't overflow for this dataset; guard vs OOB
            float s1, c1;
            sincosf(phi[i], &s1, &c1);
            const float* tp = pre + (size_t)i * NFR;
            const int slot = dst * MAXDEG + rank;
            float4* rp = recs + (size_t)slot * 3;
            rp[0] = make_float4(tp[0], tp[1], tp[2], tp[3]);
            rp[1] = make_float4(tp[4], tp[5], tp[6], tp[7]);
            rp[2] = make_float4(tp[8], tp[9], c1, s1);
            srcs[slot] = srcn;
        }
    }
    if (i < WTN) {
        int j    = i & 7;
        int lane = (i >> 3) & 63;
        int grp  = i >> 9;            // 0..139 = ks*5 + nt
        int ks   = grp / 5;
        int nt   = grp % 5;
        int quad = lane >> 4;
        int lrow = lane & 15;
        int n    = 16 * nt + lrow;    // output index op
        int k    = 32 * ks + 8 * quad + j;
        int o = n / 5, p = n % 5;
        float v1, v2;
        if (k < 800) {                // edge part: k = cq*10 + fr
            int cq = k / 10, fr = k % 10;
            int c = cq / 5, q = cq % 5;
            int f = fr >> 1, r = fr & 1;
            int src = ((((o * NC + c) * NQ + p) * NQ + q) * 5 + f) * 2 + r;
            v1 = W1[src]; v2 = W2[src];
        } else if (k < 880) {         // self part: k = 800 + cq
            int cq = k - 800;
            int c = cq / 5, q = cq % 5;
            int src = ((o * NC + c) * NQ + p) * NQ + q;
            v1 = Ws1[src]; v2 = Ws2[src];
        } else {                      // pad
            v1 = 0.0f; v2 = 0.0f;
        }
        Wt1[i] = f2h_u(v1); Wt2[i] = f2h_u(v2);
    }
}

// ---------------------------------------------------------------------------
// layer_fused v22 (SESSION BEST, locked in): 8 nodes / 512 threads,
// 1 wave/node, wave-uniform SGPR records, 4 blocks/CU, depth-2 record
// pipeline + depth-1 x pipeline. Verified 145.2 us total.
//
// Plateau documentation (R13-R16): the aggregation loop is latency-bound at
// FULL occupancy (R15 counters on the vector-pipe variant: VALUBusy 27.6%,
// MfmaUtil 2.2%, HBM 5%). ~13 us of each ~40 us layer is VALU issue; the
// rest is exposed load latency that resisted five restructures:
//   v23 2-wave/node split      +5.5 us (prologue amortization loss)
//   v24 depth-2 x pipeline     +3.2 us (SMEM lgkmcnt(0) drains kill prefetch)
//   v25 scalar->vector records +35  us (per-edge VMEM + rotation movs)
//   v26 readlane batching      +10.9us (12 v_readlane/edge doubles VALU)
//   v21 cooperative fusion     failed correctness (launch fragility)
// Mechanism: wave-uniform record loads compile to s_load; SMEM returns
// out-of-order so the compiler drains lgkmcnt(0) before each use — software
// prefetch cannot deepen the scalar pipe. Moving streams to the vector pipe
// costs more issue slots than the latency it hides. TLP is already at the
// 32-waves/CU hardware cap. Remaining total = ~45-50 us harness poison-fill
// (in-stream, uncontrollable) + prep ~8 + gaps ~9 + 2 x ~40 us layers.
// ---------------------------------------------------------------------------
__global__ __launch_bounds__(512)
void layer_fused(const float* __restrict__ xin, const int* __restrict__ srcs,
                 const float4* __restrict__ recs, const int* __restrict__ cnt,
                 const unsigned short* __restrict__ Wt, const float* __restrict__ b,
                 const float* __restrict__ res,   // residual (x) or nullptr
                 float* __restrict__ outp) {
    __shared__ __align__(16) unsigned short A_s[NPB * APAD];  // 14,976 B
    __shared__ float y_s[NPB * OP];                           //  2,560 B

    const int tid = threadIdx.x;
    const int n0 = blockIdx.x * NPB;             // NN = 1250*8 exactly
    const int wid = RFL(tid >> 6);               // wave id = local node (SGPR)
    const int lane = tid & 63;
    const int n = n0 + wid;

    // ---- lane roles (lanes 48..63 clamped to in-bounds dummy work) ----
    const int l48 = (lane < 48) ? lane : 0;
    const int c   = l48 / 3;
    const int g   = l48 - 3 * c;                 // 0,1,2
    const int cqA = 5 * c + ((g == 0) ? 0 : (g == 1) ? 1 : 3);
    const int cqB = cqA + 1;                     // partner (ignored for g==0)
    const bool hi = (g == 2);

    const int base = n * MAXDEG;
    int deg = RFL(cnt[n]);
    if (deg > MAXDEG) deg = MAXDEG;

    float accA[10], accB[10];
    #pragma unroll
    for (int f = 0; f < 10; ++f) { accA[f] = 0.f; accB[f] = 0.f; }

    // EDGE: record floats are SGPR (uniform); xa/xb per-lane VGPR loads.
#define EDGE_FMA(r0, r1, r2, xa, xb)                                          \
    do {                                                                      \
        const float c1 = (r2).z, s1 = (r2).w;                                 \
        const float c2 = c1 * c1 - s1 * s1;                                   \
        const float s2 = 2.0f * c1 * s1;                                      \
        const float cs = hi ? c2 : c1;                                        \
        const float sn = hi ? s2 : s1;                                        \
        const float xtA = (g == 0) ? (xa) : (cs * (xa) - sn * (xb));          \
        const float xtB = sn * (xa) + cs * (xb);                              \
        accA[0] += xtA * (r0).x;  accB[0] += xtB * (r0).x;                    \
        accA[1] += xtA * (r0).y;  accB[1] += xtB * (r0).y;                    \
        accA[2] += xtA * (r0).z;  accB[2] += xtB * (r0).z;                    \
        accA[3] += xtA * (r0).w;  accB[3] += xtB * (r0).w;                    \
        accA[4] += xtA * (r1).x;  accB[4] += xtB * (r1).x;                    \
        accA[5] += xtA * (r1).y;  accB[5] += xtB * (r1).y;                    \
        accA[6] += xtA * (r1).z;  accB[6] += xtB * (r1).z;                    \
        accA[7] += xtA * (r1).w;  accB[7] += xtB * (r1).w;                    \
        accA[8] += xtA * (r2).x;  accB[8] += xtB * (r2).x;                    \
        accA[9] += xtA * (r2).y;  accB[9] += xtB * (r2).y;                    \
    } while (0)

    if (deg > 0) {
        // slot(i): clamped bucket index (prefetch-safe, always in-bounds)
        #define SLOT(i) (base + (((i) < deg) ? (i) : (deg - 1)))
        // ---- depth-2 prologue: windows 0 (slots 0,1) and 1 (slots 2,3) ----
        int sA0 = RFL(srcs[SLOT(0)]);
        int sB0 = RFL(srcs[SLOT(1)]);
        int sA1 = RFL(srcs[SLOT(2)]);
        int sB1 = RFL(srcs[SLOT(3)]);
        const float4* p;
        p = recs + (size_t)SLOT(0) * 3; float4 rA0a = p[0], rA0b = p[1], rA0c = p[2];
        p = recs + (size_t)SLOT(1) * 3; float4 rB0a = p[0], rB0b = p[1], rB0c = p[2];
        p = recs + (size_t)SLOT(2) * 3; float4 rA1a = p[0], rA1b = p[1], rA1c = p[2];
        p = recs + (size_t)SLOT(3) * 3; float4 rB1a = p[0], rB1b = p[1], rB1c = p[2];
        const float* xr;
        xr = xin + (size_t)sA0 * CQ; float xaA = xr[cqA], xbA = xr[cqB];
        xr = xin + (size_t)sB0 * CQ; float xaB = xr[cqA], xbB = xr[cqB];

        int i = 0;
        for (; i + 2 <= deg; i += 2) {
            // prefetch srcs window w+2
            const int nsA = RFL(srcs[SLOT(i + 4)]);
            const int nsB = RFL(srcs[SLOT(i + 5)]);
            // prefetch x window w+1 (addresses ready: sA1/sB1)
            const float* x1 = xin + (size_t)sA1 * CQ;
            const float* x2 = xin + (size_t)sB1 * CQ;
            const float nxaA = x1[cqA], nxbA = x1[cqB];
            const float nxaB = x2[cqA], nxbB = x2[cqB];
            // prefetch recs window w+2
            const float4* q1 = recs + (size_t)SLOT(i + 4) * 3;
            const float4* q2 = recs + (size_t)SLOT(i + 5) * 3;
            const float4 nrAa = q1[0], nrAb = q1[1], nrAc = q1[2];
            const float4 nrBa = q2[0], nrBb = q2[1], nrBc = q2[2];
            // compute window w (slot order preserved)
            EDGE_FMA(rA0a, rA0b, rA0c, xaA, xbA);
            EDGE_FMA(rB0a, rB0b, rB0c, xaB, xbB);
            // rotate pipeline state
            sA0 = sA1; sB0 = sB1; sA1 = nsA; sB1 = nsB;
            xaA = nxaA; xbA = nxbA; xaB = nxaB; xbB = nxbB;
            rA0a = rA1a; rA0b = rA1b; rA0c = rA1c;
            rB0a = rB1a; rB0b = rB1b; rB0c = rB1c;
            rA1a = nrAa; rA1b = nrAb; rA1c = nrAc;
            rB1a = nrBa; rB1b = nrBb; rB1c = nrBc;
        }
        if (deg & 1) {   // tail edge deg-1: window-0 state holds slot(deg-1)
            EDGE_FMA(rA0a, rA0b, rA0c, xaA, xbA);
        }
        #undef SLOT
    }
#undef EDGE_FMA

    // ---- A-row write (k = cq*10 + fr), self column, zero pad ----
    if (lane < 48) {
        unsigned* awA = (unsigned*)&A_s[wid * APAD + cqA * 10];
        awA[0] = pack2h(accA[0], accA[1]);
        awA[1] = pack2h(accA[2], accA[3]);
        awA[2] = pack2h(accA[4], accA[5]);
        awA[3] = pack2h(accA[6], accA[7]);
        awA[4] = pack2h(accA[8], accA[9]);
        A_s[wid * APAD + 800 + cqA] = f2h_u(xin[(size_t)n * CQ + cqA]);
        if (g != 0) {
            unsigned* awB = (unsigned*)&A_s[wid * APAD + cqB * 10];
            awB[0] = pack2h(accB[0], accB[1]);
            awB[1] = pack2h(accB[2], accB[3]);
            awB[2] = pack2h(accB[4], accB[5]);
            awB[3] = pack2h(accB[6], accB[7]);
            awB[4] = pack2h(accB[8], accB[9]);
            A_s[wid * APAD + 800 + cqB] = f2h_u(xin[(size_t)n * CQ + cqB]);
        }
    }
    if (lane < 16) A_s[wid * APAD + 880 + lane] = 0;

    __syncthreads();

    // ---- GEMM: y[8 x 80] = A_s[8 x 896] @ B'[896 x 80] (waves 0-4) ----
    // A row = lrow&7 (rows 8-15 duplicate rows 0-7; D rows 8-15 discarded).
    if (tid < 320) {
        const int nt = tid >> 6, lq = tid & 63;
        const int lrow = lq & 15, quad = lq >> 4;
        const int arow = lrow & 7;
        const f16x8* __restrict__ wf = (const f16x8*)Wt;
        f32x4 acc = (f32x4){0.f, 0.f, 0.f, 0.f};
        #pragma unroll 4
        for (int ks = 0; ks < KS; ++ks) {
            f16x8 bfrag = wf[(ks * 5 + nt) * 64 + lq];
            f16x8 a = *(const f16x8*)(&A_s[arow * APAD + 32 * ks + 8 * quad]);
            acc = __builtin_amdgcn_mfma_f32_16x16x32_f16(a, bfrag, acc, 0, 0, 0);
        }
        const int op = 16 * nt + lrow;
        const float bias = (op % 5 == 0) ? b[op / 5] : 0.0f;
        if (quad < 2) {                          // D rows 0..7 only
            #pragma unroll
            for (int r = 0; r < 4; ++r)
                y_s[(quad * 4 + r) * OP + op] = acc[r] + bias;
        }
    }
    __syncthreads();

    // ---- epilogue: 128 threads, one (node, channel) each ----
    if (tid < 128) {
        const int nl = tid >> 4;                 // node 0..7
        const int ch = tid & 15;                 // channel
        const float* vp = &y_s[nl * OP + ch * 5];
        float a0 = vp[0], a1 = vp[1], a2 = vp[2], a3 = vp[3], a4 = vp[4];
        if (res != nullptr) {
            const float* rp = res + (size_t)(n0 + nl) * CQ + ch * 5;
            a0 += rp[0]; a1 += rp[1]; a2 += rp[2]; a3 += rp[3]; a4 += rp[4];
        }
        float o0 = 0.f, o1 = 0.f, o2 = 0.f, o3 = 0.f, o4 = 0.f;
        #pragma unroll
        for (int k = 0; k < 7; ++k) {
            float th = (float)(2.0 * M_PI / 7.0) * (float)k;
            float c1k = cosf(th), s1k = sinf(th);
            float c2k = cosf(2.0f * th), s2k = sinf(2.0f * th);
            float s = a0 + a1 * c1k + a2 * s1k + a3 * c2k + a4 * s2k;
            s = fmaxf(s, 0.0f);
            o0 += s;
            o1 += s * c1k; o2 += s * s1k;
            o3 += s * c2k; o4 += s * s2k;
        }
        const float i7 = 1.0f / 7.0f, t7 = 2.0f / 7.0f;
        float* po = outp + (size_t)(n0 + nl) * OP + ch * 5;
        po[0] = o0 * i7;
        po[1] = o1 * t7; po[2] = o2 * t7;
        po[3] = o3 * t7; po[4] = o4 * t7;
    }
}

// ---------------------------------------------------------------------------
extern "C" void kernel_launch(void* const* d_in, const int* in_sizes, int n_in,
                              void* d_out, int out_size, void* d_ws, size_t ws_size,
                              hipStream_t stream) {
    const float* x    = (const float*)d_in[0];
    const int*   ei   = (const int*)d_in[1];      // int inputs arrive as int32
    const float* pre  = (const float*)d_in[2];
    const float* phi  = (const float*)d_in[3];
    const float* W1   = (const float*)d_in[4];
    const float* b1   = (const float*)d_in[5];
    const float* Ws1  = (const float*)d_in[6];
    const float* W2   = (const float*)d_in[7];
    const float* b2   = (const float*)d_in[8];
    const float* Ws2  = (const float*)d_in[9];
    float* out = (float*)d_out;

    // Workspace layout (~37 MB of the 256 MB ws)
    unsigned short* Wt1 = (unsigned short*)d_ws;            // 143.4 KB
    unsigned short* Wt2 = Wt1 + WTN;                        // 143.4 KB
    float* h  = (float*)(Wt2 + WTN);                        // 3.2 MB
    float4* recs = (float4*)(h + (size_t)NN * OP);          // 30.72 MB (16B aligned)
    int* srcs   = (int*)(recs + (size_t)NN * MAXDEG * 3);   // 2.56 MB
    int* cnt    = srcs + (size_t)NN * MAXDEG;               // 40 KB

    // 4-dispatch chain: memset -> prep_all -> layer1 -> layer2
    hipMemsetAsync(cnt, 0, NN * sizeof(int), stream);
    prep_all<<<(NE + 255) / 256, 256, 0, stream>>>(ei, phi, pre, W1, Ws1, W2, Ws2,
                                                   cnt, srcs, recs, Wt1, Wt2);
    layer_fused<<<NN / NPB, 512, 0, stream>>>(x, srcs, recs, cnt, Wt1, b1, nullptr, h);
    layer_fused<<<NN / NPB, 512, 0, stream>>>(h, srcs, recs, cnt, Wt2, b2, x, out);
}